// Round 8
// baseline (760.559 us; speedup 1.0000x reference)
//
#include <hip/hip_runtime.h>

// KG attention, 3 hops.
//  - softmax denom & cnt cancel under L2 normalize: agg_next = normalize(sum_e exp(att-m)*X_e)
//  - agg in bf16 between hops; eemb pre-converted to bf16
//  - CSR by head; nodes partitioned into blocks by row_off[n]/96 -> block tile <= 128 edges
//  - k_fused: stage X (LDS) -> S=X@kwT MFMA (qh preloaded in 2 reg batches) -> att in LDS
//    -> segment softmax -> weighted sum from LDS X -> normalize -> aggb_next only
//  - k_out (once): out = 3*entity + agg1 + agg2 + agg3
// Workspace ~136.7 MB.

#define DD 128
#define CAP1 96

typedef unsigned short u16;
typedef unsigned int u32;
typedef __attribute__((ext_vector_type(8))) __bf16 bf16x8;
typedef __attribute__((ext_vector_type(4))) float f32x4;

__device__ __forceinline__ float bf2f(u16 u) { return __uint_as_float(((u32)u) << 16); }
__device__ __forceinline__ u16 f2bf(float f) {
    u32 u = __float_as_uint(f);
    u += 0x7FFFu + ((u >> 16) & 1u);   // RNE
    return (u16)(u >> 16);
}
__device__ __forceinline__ u32 cvt_pk_bf16(float a, float b) {
    u32 r;
    asm("v_cvt_pk_bf16_f32 %0, %1, %2" : "=v"(r) : "v"(a), "v"(b));
    return r;
}
// elementwise product of two bf16 pairs -> bf16 pair
__device__ __forceinline__ u32 mul_bf_bf(u32 a2, u32 b2) {
    float lo = bf2f((u16)(a2 & 0xffffu)) * bf2f((u16)(b2 & 0xffffu));
    float hi = bf2f((u16)(a2 >> 16)) * bf2f((u16)(b2 >> 16));
    return cvt_pk_bf16(lo, hi);
}
__device__ __forceinline__ float fast_tanh(float x) {
    float e = __builtin_amdgcn_exp2f(x * 2.8853900817779268f);  // e^{2x}
    float r = __builtin_amdgcn_rcpf(e + 1.f);
    return __builtin_fmaf(-2.f, r, 1.f);
}

// ------------------- f32 -> bf16 pack (entity seed, eemb) -------------------------------
__global__ void k_cvt(const float* __restrict__ src, u16* __restrict__ dst, int n8) {
    int i = blockIdx.x * blockDim.x + threadIdx.x;
    if (i >= n8) return;
    float4 a = ((const float4*)src)[i * 2];
    float4 b = ((const float4*)src)[i * 2 + 1];
    u32 pk[4] = {cvt_pk_bf16(a.x, a.y), cvt_pk_bf16(a.z, a.w),
                 cvt_pk_bf16(b.x, b.y), cvt_pk_bf16(b.z, b.w)};
    ((uint4*)dst)[i] = *(uint4*)pk;
}

// ------------------- final output: out = 3*entity + a1 + a2 + a3 ------------------------
__global__ void k_out(const u16* __restrict__ a1, const u16* __restrict__ a2,
                      const u16* __restrict__ a3, const float* __restrict__ entity,
                      float* __restrict__ out, int n8) {
    int i = blockIdx.x * blockDim.x + threadIdx.x;
    if (i >= n8) return;
    uint4 x1 = ((const uint4*)a1)[i];
    uint4 x2 = ((const uint4*)a2)[i];
    uint4 x3 = ((const uint4*)a3)[i];
    float4 e0 = ((const float4*)entity)[i * 2];
    float4 e1 = ((const float4*)entity)[i * 2 + 1];
    float o[8];
    const u32 xs1[4] = {x1.x, x1.y, x1.z, x1.w};
    const u32 xs2[4] = {x2.x, x2.y, x2.z, x2.w};
    const u32 xs3[4] = {x3.x, x3.y, x3.z, x3.w};
    const float es[8] = {e0.x, e0.y, e0.z, e0.w, e1.x, e1.y, e1.z, e1.w};
    #pragma unroll
    for (int c = 0; c < 4; ++c) {
        o[c * 2 + 0] = 3.f * es[c * 2 + 0] + bf2f((u16)(xs1[c] & 0xffffu)) +
                       bf2f((u16)(xs2[c] & 0xffffu)) + bf2f((u16)(xs3[c] & 0xffffu));
        o[c * 2 + 1] = 3.f * es[c * 2 + 1] + bf2f((u16)(xs1[c] >> 16)) +
                       bf2f((u16)(xs2[c] >> 16)) + bf2f((u16)(xs3[c] >> 16));
    }
    ((float4*)out)[i * 2]     = *(float4*)&o[0];
    ((float4*)out)[i * 2 + 1] = *(float4*)&o[4];
}

// ------------------- CSR build (once per call; head is hop-invariant) -------------------
__global__ void k_hist(const int* __restrict__ head, int E, int* __restrict__ counts) {
    int e = blockIdx.x * blockDim.x + threadIdx.x;
    if (e < E) atomicAdd(&counts[head[e]], 1);
}

__global__ void k_scan_a(const int* __restrict__ counts, int N, int* __restrict__ row_off,
                         int* __restrict__ partials) {
    __shared__ int sw[16];
    int i = blockIdx.x * 1024 + threadIdx.x;
    int v = (i < N) ? counts[i] : 0;
    int lane = threadIdx.x & 63, wid = threadIdx.x >> 6;
    int x = v;
    #pragma unroll
    for (int off = 1; off < 64; off <<= 1) {
        int t = __shfl_up(x, off);
        if (lane >= off) x += t;
    }
    if (lane == 63) sw[wid] = x;
    __syncthreads();
    if (threadIdx.x == 0) {
        int run = 0;
        for (int w0 = 0; w0 < 16; w0++) { int t = sw[w0]; sw[w0] = run; run += t; }
        partials[blockIdx.x] = run;
    }
    __syncthreads();
    if (i < N) row_off[i] = x - v + sw[wid];   // chunk-local exclusive
}
__global__ void k_scan_b(int* __restrict__ partials, int nch) {
    if (blockIdx.x == 0 && threadIdx.x == 0) {
        int run = 0;
        for (int c = 0; c < nch; c++) { int t = partials[c]; partials[c] = run; run += t; }
    }
}
__global__ void k_scan_c(int* __restrict__ row_off, const int* __restrict__ partials, int N, int E) {
    int i = blockIdx.x * 1024 + threadIdx.x;
    if (i < N) row_off[i] += partials[blockIdx.x];
    if (i == 0) row_off[N] = E;
}
__global__ void k_fill(const int* __restrict__ head, const int* __restrict__ tail,
                       const int* __restrict__ etype, int E, const int* __restrict__ row_off,
                       int* __restrict__ cursor, int* __restrict__ c_head,
                       int* __restrict__ c_tail, int* __restrict__ c_type) {
    int e = blockIdx.x * blockDim.x + threadIdx.x;
    if (e >= E) return;
    int h = head[e];
    int p = row_off[h] + atomicAdd(&cursor[h], 1);
    c_head[p] = h; c_tail[p] = tail[e]; c_type[p] = etype[e];
}

// node -> owning block (floor(start/CAP1)); block covers whole nodes, tile <= 128 edges
__global__ void k_blk(const int* __restrict__ row_off, int N,
                      int* __restrict__ blk_n0, int* __restrict__ blk_n1) {
    int n = blockIdx.x * blockDim.x + threadIdx.x;
    if (n >= N) return;
    int b = row_off[n] / CAP1;
    atomicMin(&blk_n0[b], n);
    atomicMax(&blk_n1[b], n + 1);
}

// ------------------- weight prep -------------------------------------------------------
__global__ void k_prep_swz(const float* __restrict__ src, u16* __restrict__ dst_swz) {
    int idx = blockIdx.x * 256 + threadIdx.x;
    if (idx >= DD * DD) return;
    int n = idx >> 7, k = idx & 127;
    float v = src[k * DD + n];
    int byte = (n * 256 + k * 2) ^ ((n & 7) << 4);
    dst_swz[byte >> 1] = f2bf(v);
}
__global__ void k_prep_plain(const float* __restrict__ src, u16* __restrict__ dst) {
    int idx = blockIdx.x * 256 + threadIdx.x;
    if (idx >= DD * DD) return;
    int n = idx >> 7, k = idx & 127;
    dst[n * DD + k] = f2bf(src[k * DD + n]);
}

// ------------------- qh = aggb @ q_w  (bf16 out) via MFMA -------------------------------
__global__ void __launch_bounds__(256) k_qproj(const u16* __restrict__ aggb,
                                               const uint4* __restrict__ qwT_swz,
                                               u16* __restrict__ qh, int N) {
    __shared__ u16 sA[DD * DD];    // 32 KB, swizzled bf16 rows
    __shared__ u16 sB[DD * DD];    // 32 KB, qwT swizzled
    int tid = threadIdx.x;
    {
        uint4* dst = (uint4*)sB;
        #pragma unroll
        for (int i = 0; i < 8; ++i) dst[i * 256 + tid] = qwT_swz[i * 256 + tid];
    }
    long base = (long)blockIdx.x * 128;
    int qq = tid & 3, er = tid >> 2;
    #pragma unroll
    for (int pass = 0; pass < 2; ++pass) {
        int rloc = pass * 64 + er;
        long n = base + rloc;
        int d0 = qq * 32;
        __align__(16) uint4 pk[4];
        if (n < N) {
            const uint4* ar = (const uint4*)(aggb + (size_t)n * DD + d0);
            #pragma unroll
            for (int c = 0; c < 4; ++c) pk[c] = ar[c];
        } else {
            #pragma unroll
            for (int c = 0; c < 4; ++c) pk[c] = (uint4){0u, 0u, 0u, 0u};
        }
        char* basep = (char*)sA;
        #pragma unroll
        for (int c = 0; c < 4; ++c) {
            int byte = (rloc * 256 + d0 * 2 + c * 16) ^ ((rloc & 7) << 4);
            *(uint4*)(basep + byte) = pk[c];
        }
    }
    __syncthreads();
    int lane = tid & 63, wid = tid >> 6;
    int lr = lane & 15, lg = lane >> 4;
    int rgbase = wid * 32;
    f32x4 acc[2][8];
    #pragma unroll
    for (int g = 0; g < 2; ++g)
        #pragma unroll
        for (int t = 0; t < 8; ++t) acc[g][t] = (f32x4){0.f, 0.f, 0.f, 0.f};
    const char* ab_ = (const char*)sA;
    const char* bb_ = (const char*)sB;
    int sw = (lr & 7) << 4;
    #pragma unroll
    for (int kc = 0; kc < 4; ++kc) {
        int koffb = kc * 64 + lg * 16;
        int r0 = rgbase + lr;
        bf16x8 a0 = *(const bf16x8*)(ab_ + ((r0 * 256 + koffb) ^ sw));
        bf16x8 a1 = *(const bf16x8*)(ab_ + (((r0 + 16) * 256 + koffb) ^ sw));
        #pragma unroll
        for (int t = 0; t < 8; ++t) {
            int n = t * 16 + lr;
            bf16x8 b = *(const bf16x8*)(bb_ + ((n * 256 + koffb) ^ sw));
            acc[0][t] = __builtin_amdgcn_mfma_f32_16x16x32_bf16(a0, b, acc[0][t], 0, 0, 0);
            acc[1][t] = __builtin_amdgcn_mfma_f32_16x16x32_bf16(a1, b, acc[1][t], 0, 0, 0);
        }
    }
    #pragma unroll
    for (int g = 0; g < 2; ++g)
        #pragma unroll
        for (int r = 0; r < 4; ++r) {
            long row = base + rgbase + g * 16 + lg * 4 + r;
            if (row < N) {
                u16* qrow = qh + (size_t)row * DD + lr;
                #pragma unroll
                for (int t = 0; t < 8; ++t) qrow[t * 16] = f2bf(acc[g][t][r]);
            }
        }
}

// ------------------- fused: att + segment softmax + weighted agg + normalize ------------
// Block owns nodes [n0,n1), tile = their CSR span (<=128 edges).
__global__ void __launch_bounds__(256, 4) k_fused(
        const u16* __restrict__ aggb, const u16* __restrict__ eembb,
        const u16* __restrict__ kwT, const u16* __restrict__ qh,
        const int* __restrict__ c_head, const int* __restrict__ c_tail,
        const int* __restrict__ c_type, const int* __restrict__ row_off,
        const int* __restrict__ blk_n0, const int* __restrict__ blk_n1,
        u16* __restrict__ aggb_next) {
    __shared__ u16 sX[DD * DD];    // 32 KB, swizzled bf16 X rows
    __shared__ float satt[128];
    int n0 = blk_n0[blockIdx.x];
    if (n0 == 0x7f7f7f7f) return;          // no nodes own this window
    int n1 = blk_n1[blockIdx.x];
    int p0 = row_off[n0];
    int span = min(row_off[n1] - p0, 128); // whole-node tile (degree-capped clamp)
    int tid = threadIdx.x;
    int qq = tid & 3, er = tid >> 2;       // 4 threads/edge, 32 dims each
    // ---- stage X = aggb[tail] (*) eembb[type], bf16, swizzled ----
    #pragma unroll
    for (int pass = 0; pass < 2; ++pass) {
        int eloc = pass * 64 + er;
        int d0 = qq * 32;
        __align__(16) u32 pk[16];
        if (eloc < span) {
            int p = p0 + eloc;
            int tl = c_tail[p], rl = c_type[p];
            const uint4* ar = (const uint4*)(aggb + (size_t)tl * DD + d0);
            const uint4* rr = (const uint4*)(eembb + (size_t)rl * DD + d0);
            #pragma unroll
            for (int c = 0; c < 4; ++c) {
                uint4 av = ar[c], rv = rr[c];
                pk[c * 4 + 0] = mul_bf_bf(av.x, rv.x);
                pk[c * 4 + 1] = mul_bf_bf(av.y, rv.y);
                pk[c * 4 + 2] = mul_bf_bf(av.z, rv.z);
                pk[c * 4 + 3] = mul_bf_bf(av.w, rv.w);
            }
        } else {
            #pragma unroll
            for (int i = 0; i < 16; ++i) pk[i] = 0u;
        }
        char* base = (char*)sX;
        #pragma unroll
        for (int c = 0; c < 4; ++c) {
            int byte = (eloc * 256 + d0 * 2 + c * 16) ^ ((eloc & 7) << 4);
            *(uint4*)(base + byte) = *(const uint4*)&pk[c * 4];
        }
    }
    __syncthreads();
    // ---- S = X @ kwT^T via MFMA (t-outer, acc[2] live), tanh + qh dot -> satt ----
    int lane = tid & 63, wid = tid >> 6;
    int lr = lane & 15, lg = lane >> 4;
    int egbase = wid * 32;
    const char* xb_ = (const char*)sX;
    int sw = (lr & 7) << 4;
    bf16x8 afrag[2][4];
    #pragma unroll
    for (int kc = 0; kc < 4; ++kc) {
        int koffb = kc * 64 + lg * 16;
        int r0 = egbase + lr;
        afrag[0][kc] = *(const bf16x8*)(xb_ + ((r0 * 256 + koffb) ^ sw));
        afrag[1][kc] = *(const bf16x8*)(xb_ + (((r0 + 16) * 256 + koffb) ^ sw));
    }
    int hh[8];
    #pragma unroll
    for (int g = 0; g < 2; ++g)
        #pragma unroll
        for (int r = 0; r < 4; ++r) {
            int eloc = egbase + g * 16 + lg * 4 + r;
            hh[g * 4 + r] = (eloc < span) ? c_head[p0 + eloc] : 0;
        }
    float attv[8] = {0.f, 0.f, 0.f, 0.f, 0.f, 0.f, 0.f, 0.f};
    #pragma unroll
    for (int half = 0; half < 2; ++half) {
        // batch-preload 32 qh values (8 rows x 4 cols) into 16 packed regs
        u32 qv[8][2];
        #pragma unroll
        for (int i = 0; i < 8; ++i) {
            const u16* qr = qh + (size_t)hh[i] * DD + lr;
            #pragma unroll
            for (int tp = 0; tp < 2; ++tp) {
                int t0 = half * 4 + tp * 2;
                u16 a = qr[t0 * 16];
                u16 b = qr[(t0 + 1) * 16];
                qv[i][tp] = (u32)a | ((u32)b << 16);
            }
        }
        #pragma unroll
        for (int tt = 0; tt < 4; ++tt) {
            int t = half * 4 + tt;
            f32x4 acc0 = (f32x4){0.f, 0.f, 0.f, 0.f};
            f32x4 acc1 = (f32x4){0.f, 0.f, 0.f, 0.f};
            int n = t * 16 + lr;
            #pragma unroll
            for (int kc = 0; kc < 4; ++kc) {
                int koffe = kc * 32 + lg * 8;
                bf16x8 b = *(const bf16x8*)(kwT + n * DD + koffe);
                acc0 = __builtin_amdgcn_mfma_f32_16x16x32_bf16(afrag[0][kc], b, acc0, 0, 0, 0);
                acc1 = __builtin_amdgcn_mfma_f32_16x16x32_bf16(afrag[1][kc], b, acc1, 0, 0, 0);
            }
            #pragma unroll
            for (int r = 0; r < 4; ++r) {
                u32 q0 = qv[r][tt >> 1], q1 = qv[4 + r][tt >> 1];
                u16 v0 = (tt & 1) ? (u16)(q0 >> 16) : (u16)(q0 & 0xffffu);
                u16 v1 = (tt & 1) ? (u16)(q1 >> 16) : (u16)(q1 & 0xffffu);
                attv[r]     += fast_tanh(acc0[r]) * bf2f(v0);
                attv[4 + r] += fast_tanh(acc1[r]) * bf2f(v1);
            }
        }
    }
    #pragma unroll
    for (int off = 1; off < 16; off <<= 1) {
        #pragma unroll
        for (int i = 0; i < 8; ++i) attv[i] += __shfl_xor(attv[i], off);
    }
    if (lr == 0) {
        #pragma unroll
        for (int g = 0; g < 2; ++g)
            #pragma unroll
            for (int r = 0; r < 4; ++r) {
                int eloc = egbase + g * 16 + lg * 4 + r;
                if (eloc < span) satt[eloc] = attv[g * 4 + r];
            }
    }
    __syncthreads();
    // ---- per-node: softmax max, weighted sum of LDS X rows, normalize ----
    for (int n = n0 + wid; n < n1; n += 4) {
        int s0 = row_off[n] - p0;
        int s1 = min(row_off[n + 1] - p0, 128);
        float a0 = 0.f, a1 = 0.f;
        if (s1 > s0) {
            float m = -1e30f;
            for (int p = s0; p < s1; ++p) m = fmaxf(m, satt[p]);
            for (int p = s0; p < s1; ++p) {
                float wgt = __expf(satt[p] - m);
                int byte = (p * 256 + lane * 4) ^ ((p & 7) << 4);
                u32 xv = *(const u32*)((const char*)sX + byte);
                a0 += wgt * bf2f((u16)(xv & 0xffffu));
                a1 += wgt * bf2f((u16)(xv >> 16));
            }
            float s = a0 * a0 + a1 * a1;
            #pragma unroll
            for (int off = 1; off < 64; off <<= 1) s += __shfl_xor(s, off);
            float sc = 1.f / fmaxf(sqrtf(s), 1e-12f);
            a0 *= sc; a1 *= sc;
        }
        size_t idx = (size_t)n * DD + lane * 2;
        *(u32*)(aggb_next + idx) = cvt_pk_bf16(a0, a1);
    }
}

extern "C" void kernel_launch(void* const* d_in, const int* in_sizes, int n_in,
                              void* d_out, int out_size, void* d_ws, size_t ws_size,
                              hipStream_t stream) {
    const float* entity = (const float*)d_in[0];
    const float* eemb   = (const float*)d_in[1];
    const float* qw     = (const float*)d_in[2];
    const float* kw     = (const float*)d_in[3];
    const int*   eidx   = (const int*)d_in[4];
    const int*   etype  = (const int*)d_in[5];
    const int N = in_sizes[0] / DD;
    const int E = in_sizes[5];
    const int NREL = in_sizes[1] / DD;
    const int* head = eidx;
    const int* tail = eidx + E;
    const int NB = E / CAP1 + 2;

    // workspace carve (~136.7 MB)
    char* w = (char*)d_ws;
    auto carve = [&](size_t bytes) -> void* {
        void* p = (void*)w;
        w += ((bytes + 255) / 256) * 256;
        return p;
    };
    u16* aggb0     = (u16*)carve((size_t)N * DD * 2);
    u16* aggb1     = (u16*)carve((size_t)N * DD * 2);
    u16* aggb2     = (u16*)carve((size_t)N * DD * 2);
    u16* aggb3     = (u16*)carve((size_t)N * DD * 2);
    u16* qh        = (u16*)carve((size_t)N * DD * 2);
    u16* eembb     = (u16*)carve((size_t)NREL * DD * 2);
    int* counts    = (int*)carve((size_t)N * 4);
    int* row_off   = (int*)carve((size_t)(N + 1) * 4);
    int* cursor    = (int*)carve((size_t)N * 4);
    int* c_head    = (int*)carve((size_t)E * 4);
    int* c_tail    = (int*)carve((size_t)E * 4);
    int* c_type    = (int*)carve((size_t)E * 4);
    u16* qwT_swz   = (u16*)carve((size_t)DD * DD * 2);
    u16* kwT       = (u16*)carve((size_t)DD * DD * 2);
    int* blk_n0    = (int*)carve((size_t)NB * 4);
    int* blk_n1    = (int*)carve((size_t)NB * 4);
    int* partials  = (int*)carve(4096);
    (void)ws_size; (void)n_in; (void)out_size;

    hipMemsetAsync(counts, 0, (size_t)N * 4, stream);
    hipMemsetAsync(cursor, 0, (size_t)N * 4, stream);
    hipMemsetAsync(blk_n0, 0x7f, (size_t)NB * 4, stream);
    hipMemsetAsync(blk_n1, 0, (size_t)NB * 4, stream);
    k_prep_swz<<<(DD * DD + 255) / 256, 256, 0, stream>>>(qw, qwT_swz);
    k_prep_plain<<<(DD * DD + 255) / 256, 256, 0, stream>>>(kw, kwT);
    int n8 = N * DD / 8;
    k_cvt<<<(n8 + 255) / 256, 256, 0, stream>>>(entity, aggb0, n8);
    int r8 = NREL * DD / 8;
    k_cvt<<<(r8 + 255) / 256, 256, 0, stream>>>(eemb, eembb, r8);
    k_hist<<<(E + 255) / 256, 256, 0, stream>>>(head, E, counts);
    int nch = (N + 1023) / 1024;
    k_scan_a<<<nch, 1024, 0, stream>>>(counts, N, row_off, partials);
    k_scan_b<<<1, 64, 0, stream>>>(partials, nch);
    k_scan_c<<<nch, 1024, 0, stream>>>(row_off, partials, N, E);
    k_fill<<<(E + 255) / 256, 256, 0, stream>>>(head, tail, etype, E, row_off, cursor,
                                                c_head, c_tail, c_type);
    k_blk<<<(N + 255) / 256, 256, 0, stream>>>(row_off, N, blk_n0, blk_n1);

    u16* hops[3] = {aggb1, aggb2, aggb3};
    const u16* cur = aggb0;
    for (int hop = 0; hop < 3; hop++) {
        k_qproj<<<(N + 127) / 128, 256, 0, stream>>>(cur, (const uint4*)qwT_swz, qh, N);
        k_fused<<<NB, 256, 0, stream>>>(cur, eembb, kwT, qh, c_head, c_tail, c_type,
                                        row_off, blk_n0, blk_n1, hops[hop]);
        cur = hops[hop];
    }
    k_out<<<(n8 + 255) / 256, 256, 0, stream>>>(aggb1, aggb2, aggb3, entity,
                                                (float*)d_out, n8);
}

// Round 10
// 643.386 us; speedup vs baseline: 1.1821x; 1.1821x over previous
//
#include <hip/hip_runtime.h>

// KG attention, 3 hops.  (round-7 structure + lane-parallel exact max epilogue)
//  - softmax denom & cnt cancel under L2 normalize: agg_next = normalize(sum_e exp(att-m)*X_e)
//  - agg in bf16 between hops; eemb pre-converted to bf16
//  - CSR by head; nodes partitioned into blocks by row_off[n]/96 -> block tile <= 128 edges
//  - k_fused: stage X (LDS) -> S=X@kwT MFMA -> att in LDS -> lane-parallel segment max ->
//    weighted sum from LDS X -> normalize -> out
// Workspace ~113 MB.

#define DD 128
#define CAP1 96

typedef unsigned short u16;
typedef unsigned int u32;
typedef __attribute__((ext_vector_type(8))) __bf16 bf16x8;
typedef __attribute__((ext_vector_type(4))) float f32x4;

__device__ __forceinline__ float bf2f(u16 u) { return __uint_as_float(((u32)u) << 16); }
__device__ __forceinline__ u16 f2bf(float f) {
    u32 u = __float_as_uint(f);
    u += 0x7FFFu + ((u >> 16) & 1u);   // RNE
    return (u16)(u >> 16);
}
__device__ __forceinline__ u32 cvt_pk_bf16(float a, float b) {
    u32 r;
    asm("v_cvt_pk_bf16_f32 %0, %1, %2" : "=v"(r) : "v"(a), "v"(b));
    return r;
}
// elementwise product of two bf16 pairs -> bf16 pair
__device__ __forceinline__ u32 mul_bf_bf(u32 a2, u32 b2) {
    float lo = bf2f((u16)(a2 & 0xffffu)) * bf2f((u16)(b2 & 0xffffu));
    float hi = bf2f((u16)(a2 >> 16)) * bf2f((u16)(b2 >> 16));
    return cvt_pk_bf16(lo, hi);
}
__device__ __forceinline__ float fast_tanh(float x) {
    float e = __builtin_amdgcn_exp2f(x * 2.8853900817779268f);  // e^{2x}
    float r = __builtin_amdgcn_rcpf(e + 1.f);
    return __builtin_fmaf(-2.f, r, 1.f);
}

// ------------------- f32 -> bf16 pack (entity seed, eemb) -------------------------------
__global__ void k_cvt(const float* __restrict__ src, u16* __restrict__ dst, int n8) {
    int i = blockIdx.x * blockDim.x + threadIdx.x;
    if (i >= n8) return;
    float4 a = ((const float4*)src)[i * 2];
    float4 b = ((const float4*)src)[i * 2 + 1];
    u32 pk[4] = {cvt_pk_bf16(a.x, a.y), cvt_pk_bf16(a.z, a.w),
                 cvt_pk_bf16(b.x, b.y), cvt_pk_bf16(b.z, b.w)};
    ((uint4*)dst)[i] = *(uint4*)pk;
}

// ------------------- CSR build (once per call; head is hop-invariant) -------------------
__global__ void k_hist(const int* __restrict__ head, int E, int* __restrict__ counts) {
    int e = blockIdx.x * blockDim.x + threadIdx.x;
    if (e < E) atomicAdd(&counts[head[e]], 1);
}

__global__ void k_scan_a(const int* __restrict__ counts, int N, int* __restrict__ row_off,
                         int* __restrict__ partials) {
    __shared__ int sw[16];
    int i = blockIdx.x * 1024 + threadIdx.x;
    int v = (i < N) ? counts[i] : 0;
    int lane = threadIdx.x & 63, wid = threadIdx.x >> 6;
    int x = v;
    #pragma unroll
    for (int off = 1; off < 64; off <<= 1) {
        int t = __shfl_up(x, off);
        if (lane >= off) x += t;
    }
    if (lane == 63) sw[wid] = x;
    __syncthreads();
    if (threadIdx.x == 0) {
        int run = 0;
        for (int w0 = 0; w0 < 16; w0++) { int t = sw[w0]; sw[w0] = run; run += t; }
        partials[blockIdx.x] = run;
    }
    __syncthreads();
    if (i < N) row_off[i] = x - v + sw[wid];   // chunk-local exclusive
}
__global__ void k_scan_b(int* __restrict__ partials, int nch) {
    if (blockIdx.x == 0 && threadIdx.x == 0) {
        int run = 0;
        for (int c = 0; c < nch; c++) { int t = partials[c]; partials[c] = run; run += t; }
    }
}
__global__ void k_scan_c(int* __restrict__ row_off, const int* __restrict__ partials, int N, int E) {
    int i = blockIdx.x * 1024 + threadIdx.x;
    if (i < N) row_off[i] += partials[blockIdx.x];
    if (i == 0) row_off[N] = E;
}
__global__ void k_fill(const int* __restrict__ head, const int* __restrict__ tail,
                       const int* __restrict__ etype, int E, const int* __restrict__ row_off,
                       int* __restrict__ cursor, int* __restrict__ c_head,
                       int* __restrict__ c_tail, int* __restrict__ c_type) {
    int e = blockIdx.x * blockDim.x + threadIdx.x;
    if (e >= E) return;
    int h = head[e];
    int p = row_off[h] + atomicAdd(&cursor[h], 1);
    c_head[p] = h; c_tail[p] = tail[e]; c_type[p] = etype[e];
}

// node -> owning block (floor(start/CAP1)); block covers whole nodes, tile <= 128 edges
__global__ void k_blk(const int* __restrict__ row_off, int N,
                      int* __restrict__ blk_n0, int* __restrict__ blk_n1) {
    int n = blockIdx.x * blockDim.x + threadIdx.x;
    if (n >= N) return;
    int b = row_off[n] / CAP1;
    atomicMin(&blk_n0[b], n);
    atomicMax(&blk_n1[b], n + 1);
}

// ------------------- weight prep -------------------------------------------------------
__global__ void k_prep_swz(const float* __restrict__ src, u16* __restrict__ dst_swz) {
    int idx = blockIdx.x * 256 + threadIdx.x;
    if (idx >= DD * DD) return;
    int n = idx >> 7, k = idx & 127;
    float v = src[k * DD + n];
    int byte = (n * 256 + k * 2) ^ ((n & 7) << 4);
    dst_swz[byte >> 1] = f2bf(v);
}
__global__ void k_prep_plain(const float* __restrict__ src, u16* __restrict__ dst) {
    int idx = blockIdx.x * 256 + threadIdx.x;
    if (idx >= DD * DD) return;
    int n = idx >> 7, k = idx & 127;
    dst[n * DD + k] = f2bf(src[k * DD + n]);
}

// ------------------- qh = aggb @ q_w  (bf16 out) via MFMA -------------------------------
__global__ void __launch_bounds__(256) k_qproj(const u16* __restrict__ aggb,
                                               const uint4* __restrict__ qwT_swz,
                                               u16* __restrict__ qh, int N) {
    __shared__ u16 sA[DD * DD];    // 32 KB, swizzled bf16 rows
    __shared__ u16 sB[DD * DD];    // 32 KB, qwT swizzled
    int tid = threadIdx.x;
    {
        uint4* dst = (uint4*)sB;
        #pragma unroll
        for (int i = 0; i < 8; ++i) dst[i * 256 + tid] = qwT_swz[i * 256 + tid];
    }
    long base = (long)blockIdx.x * 128;
    int qq = tid & 3, er = tid >> 2;
    #pragma unroll
    for (int pass = 0; pass < 2; ++pass) {
        int rloc = pass * 64 + er;
        long n = base + rloc;
        int d0 = qq * 32;
        __align__(16) uint4 pk[4];
        if (n < N) {
            const uint4* ar = (const uint4*)(aggb + (size_t)n * DD + d0);
            #pragma unroll
            for (int c = 0; c < 4; ++c) pk[c] = ar[c];
        } else {
            #pragma unroll
            for (int c = 0; c < 4; ++c) pk[c] = (uint4){0u, 0u, 0u, 0u};
        }
        char* basep = (char*)sA;
        #pragma unroll
        for (int c = 0; c < 4; ++c) {
            int byte = (rloc * 256 + d0 * 2 + c * 16) ^ ((rloc & 7) << 4);
            *(uint4*)(basep + byte) = pk[c];
        }
    }
    __syncthreads();
    int lane = tid & 63, wid = tid >> 6;
    int lr = lane & 15, lg = lane >> 4;
    int rgbase = wid * 32;
    f32x4 acc[2][8];
    #pragma unroll
    for (int g = 0; g < 2; ++g)
        #pragma unroll
        for (int t = 0; t < 8; ++t) acc[g][t] = (f32x4){0.f, 0.f, 0.f, 0.f};
    const char* ab_ = (const char*)sA;
    const char* bb_ = (const char*)sB;
    int sw = (lr & 7) << 4;
    #pragma unroll
    for (int kc = 0; kc < 4; ++kc) {
        int koffb = kc * 64 + lg * 16;
        int r0 = rgbase + lr;
        bf16x8 a0 = *(const bf16x8*)(ab_ + ((r0 * 256 + koffb) ^ sw));
        bf16x8 a1 = *(const bf16x8*)(ab_ + (((r0 + 16) * 256 + koffb) ^ sw));
        #pragma unroll
        for (int t = 0; t < 8; ++t) {
            int n = t * 16 + lr;
            bf16x8 b = *(const bf16x8*)(bb_ + ((n * 256 + koffb) ^ sw));
            acc[0][t] = __builtin_amdgcn_mfma_f32_16x16x32_bf16(a0, b, acc[0][t], 0, 0, 0);
            acc[1][t] = __builtin_amdgcn_mfma_f32_16x16x32_bf16(a1, b, acc[1][t], 0, 0, 0);
        }
    }
    #pragma unroll
    for (int g = 0; g < 2; ++g)
        #pragma unroll
        for (int r = 0; r < 4; ++r) {
            long row = base + rgbase + g * 16 + lg * 4 + r;
            if (row < N) {
                u16* qrow = qh + (size_t)row * DD + lr;
                #pragma unroll
                for (int t = 0; t < 8; ++t) qrow[t * 16] = f2bf(acc[g][t][r]);
            }
        }
}

// ------------------- fused: att + segment softmax + weighted agg + normalize ------------
// Block owns nodes [n0,n1), tile = their CSR span (<=128 edges).
__global__ void __launch_bounds__(256, 4) k_fused(
        const u16* __restrict__ aggb, const u16* __restrict__ eembb,
        const u16* __restrict__ kwT, const u16* __restrict__ qh,
        const int* __restrict__ c_head, const int* __restrict__ c_tail,
        const int* __restrict__ c_type, const int* __restrict__ row_off,
        const int* __restrict__ blk_n0, const int* __restrict__ blk_n1,
        const float* __restrict__ entity,
        u16* __restrict__ aggb_next, float* __restrict__ outacc, int mode) {
    __shared__ u16 sX[DD * DD];    // 32 KB, swizzled bf16 X rows
    __shared__ float satt[128];
    int n0 = blk_n0[blockIdx.x];
    if (n0 == 0x7f7f7f7f) return;          // no nodes own this window
    int n1 = blk_n1[blockIdx.x];
    int p0 = row_off[n0];
    int span = min(row_off[n1] - p0, 128); // whole-node tile (degree-capped clamp)
    int tid = threadIdx.x;
    int qq = tid & 3, er = tid >> 2;       // 4 threads/edge, 32 dims each
    // ---- stage X = aggb[tail] (*) eembb[type], bf16, swizzled ----
    #pragma unroll
    for (int pass = 0; pass < 2; ++pass) {
        int eloc = pass * 64 + er;
        int d0 = qq * 32;
        __align__(16) u32 pk[16];
        if (eloc < span) {
            int p = p0 + eloc;
            int tl = c_tail[p], rl = c_type[p];
            const uint4* ar = (const uint4*)(aggb + (size_t)tl * DD + d0);
            const uint4* rr = (const uint4*)(eembb + (size_t)rl * DD + d0);
            #pragma unroll
            for (int c = 0; c < 4; ++c) {
                uint4 av = ar[c], rv = rr[c];
                pk[c * 4 + 0] = mul_bf_bf(av.x, rv.x);
                pk[c * 4 + 1] = mul_bf_bf(av.y, rv.y);
                pk[c * 4 + 2] = mul_bf_bf(av.z, rv.z);
                pk[c * 4 + 3] = mul_bf_bf(av.w, rv.w);
            }
        } else {
            #pragma unroll
            for (int i = 0; i < 16; ++i) pk[i] = 0u;
        }
        char* base = (char*)sX;
        #pragma unroll
        for (int c = 0; c < 4; ++c) {
            int byte = (eloc * 256 + d0 * 2 + c * 16) ^ ((eloc & 7) << 4);
            *(uint4*)(base + byte) = *(const uint4*)&pk[c * 4];
        }
    }
    __syncthreads();
    // ---- S = X @ kwT^T via MFMA (t-outer, acc[2] live), tanh + qh dot -> satt ----
    int lane = tid & 63, wid = tid >> 6;
    int lr = lane & 15, lg = lane >> 4;
    int egbase = wid * 32;
    const char* xb_ = (const char*)sX;
    int sw = (lr & 7) << 4;
    bf16x8 afrag[2][4];
    #pragma unroll
    for (int kc = 0; kc < 4; ++kc) {
        int koffb = kc * 64 + lg * 16;
        int r0 = egbase + lr;
        afrag[0][kc] = *(const bf16x8*)(xb_ + ((r0 * 256 + koffb) ^ sw));
        afrag[1][kc] = *(const bf16x8*)(xb_ + (((r0 + 16) * 256 + koffb) ^ sw));
    }
    int hh[8];
    #pragma unroll
    for (int g = 0; g < 2; ++g)
        #pragma unroll
        for (int r = 0; r < 4; ++r) {
            int eloc = egbase + g * 16 + lg * 4 + r;
            hh[g * 4 + r] = (eloc < span) ? c_head[p0 + eloc] : 0;
        }
    float attv[8] = {0.f, 0.f, 0.f, 0.f, 0.f, 0.f, 0.f, 0.f};
    #pragma unroll
    for (int t = 0; t < 8; ++t) {
        f32x4 acc0 = (f32x4){0.f, 0.f, 0.f, 0.f};
        f32x4 acc1 = (f32x4){0.f, 0.f, 0.f, 0.f};
        int n = t * 16 + lr;
        #pragma unroll
        for (int kc = 0; kc < 4; ++kc) {
            int koffe = kc * 32 + lg * 8;
            bf16x8 b = *(const bf16x8*)(kwT + n * DD + koffe);
            acc0 = __builtin_amdgcn_mfma_f32_16x16x32_bf16(afrag[0][kc], b, acc0, 0, 0, 0);
            acc1 = __builtin_amdgcn_mfma_f32_16x16x32_bf16(afrag[1][kc], b, acc1, 0, 0, 0);
        }
        #pragma unroll
        for (int r = 0; r < 4; ++r) {
            attv[r]     += fast_tanh(acc0[r]) * bf2f(qh[(size_t)hh[r] * DD + t * 16 + lr]);
            attv[4 + r] += fast_tanh(acc1[r]) * bf2f(qh[(size_t)hh[4 + r] * DD + t * 16 + lr]);
        }
    }
    #pragma unroll
    for (int off = 1; off < 16; off <<= 1) {
        #pragma unroll
        for (int i = 0; i < 8; ++i) attv[i] += __shfl_xor(attv[i], off);
    }
    if (lr == 0) {
        #pragma unroll
        for (int g = 0; g < 2; ++g)
            #pragma unroll
            for (int r = 0; r < 4; ++r) {
                int eloc = egbase + g * 16 + lg * 4 + r;
                if (eloc < span) satt[eloc] = attv[g * 4 + r];
            }
    }
    __syncthreads();
    // ---- per-node: lane-parallel EXACT max, weighted sum of LDS X rows, normalize ----
    for (int n = n0 + wid; n < n1; n += 4) {
        int s0 = row_off[n] - p0;
        int s1 = min(row_off[n + 1] - p0, 128);
        float a0 = 0.f, a1 = 0.f;
        if (s1 > s0) {
            // exact segment max: lane-strided conflict-free read + shfl reduce
            float mv = -1e30f;
            int pp = s0 + lane;
            if (pp < s1) mv = satt[pp];
            if (pp + 64 < s1) mv = fmaxf(mv, satt[pp + 64]);
            #pragma unroll
            for (int off = 1; off < 64; off <<= 1) mv = fmaxf(mv, __shfl_xor(mv, off));
            #pragma unroll 2
            for (int p = s0; p < s1; ++p) {
                float wgt = __expf(satt[p] - mv);
                int byte = (p * 256 + lane * 4) ^ ((p & 7) << 4);
                u32 xv = *(const u32*)((const char*)sX + byte);
                a0 += wgt * bf2f((u16)(xv & 0xffffu));
                a1 += wgt * bf2f((u16)(xv >> 16));
            }
            float s = a0 * a0 + a1 * a1;
            #pragma unroll
            for (int off = 1; off < 64; off <<= 1) s += __shfl_xor(s, off);
            float sc = 1.f / fmaxf(sqrtf(s), 1e-12f);
            a0 *= sc; a1 *= sc;
        }
        size_t idx = (size_t)n * DD + lane * 2;
        *(u32*)(aggb_next + idx) = cvt_pk_bf16(a0, a1);
        float o0, o1;
        if (mode == 0) { o0 = a0; o1 = a1; }
        else { o0 = outacc[idx] + a0; o1 = outacc[idx + 1] + a1; }
        if (mode == 2) { o0 += 3.f * entity[idx]; o1 += 3.f * entity[idx + 1]; }
        outacc[idx] = o0; outacc[idx + 1] = o1;
    }
}

extern "C" void kernel_launch(void* const* d_in, const int* in_sizes, int n_in,
                              void* d_out, int out_size, void* d_ws, size_t ws_size,
                              hipStream_t stream) {
    const float* entity = (const float*)d_in[0];
    const float* eemb   = (const float*)d_in[1];
    const float* qw     = (const float*)d_in[2];
    const float* kw     = (const float*)d_in[3];
    const int*   eidx   = (const int*)d_in[4];
    const int*   etype  = (const int*)d_in[5];
    const int N = in_sizes[0] / DD;
    const int E = in_sizes[5];
    const int NREL = in_sizes[1] / DD;
    const int* head = eidx;
    const int* tail = eidx + E;
    const int NB = E / CAP1 + 2;

    // workspace carve (~113 MB)
    char* w = (char*)d_ws;
    auto carve = [&](size_t bytes) -> void* {
        void* p = (void*)w;
        w += ((bytes + 255) / 256) * 256;
        return p;
    };
    u16* aggbA     = (u16*)carve((size_t)N * DD * 2);
    u16* aggbB     = (u16*)carve((size_t)N * DD * 2);
    u16* aggb0     = (u16*)carve((size_t)N * DD * 2);
    u16* qh        = (u16*)carve((size_t)N * DD * 2);
    u16* eembb     = (u16*)carve((size_t)NREL * DD * 2);
    int* counts    = (int*)carve((size_t)N * 4);
    int* row_off   = (int*)carve((size_t)(N + 1) * 4);
    int* cursor    = (int*)carve((size_t)N * 4);
    int* c_head    = (int*)carve((size_t)E * 4);
    int* c_tail    = (int*)carve((size_t)E * 4);
    int* c_type    = (int*)carve((size_t)E * 4);
    u16* qwT_swz   = (u16*)carve((size_t)DD * DD * 2);
    u16* kwT       = (u16*)carve((size_t)DD * DD * 2);
    int* blk_n0    = (int*)carve((size_t)NB * 4);
    int* blk_n1    = (int*)carve((size_t)NB * 4);
    int* partials  = (int*)carve(4096);
    (void)ws_size; (void)n_in; (void)out_size;

    hipMemsetAsync(counts, 0, (size_t)N * 4, stream);
    hipMemsetAsync(cursor, 0, (size_t)N * 4, stream);
    hipMemsetAsync(blk_n0, 0x7f, (size_t)NB * 4, stream);
    hipMemsetAsync(blk_n1, 0, (size_t)NB * 4, stream);
    k_prep_swz<<<(DD * DD + 255) / 256, 256, 0, stream>>>(qw, qwT_swz);
    k_prep_plain<<<(DD * DD + 255) / 256, 256, 0, stream>>>(kw, kwT);
    int n8 = N * DD / 8;
    k_cvt<<<(n8 + 255) / 256, 256, 0, stream>>>(entity, aggb0, n8);
    int r8 = NREL * DD / 8;
    k_cvt<<<(r8 + 255) / 256, 256, 0, stream>>>(eemb, eembb, r8);
    k_hist<<<(E + 255) / 256, 256, 0, stream>>>(head, E, counts);
    int nch = (N + 1023) / 1024;
    k_scan_a<<<nch, 1024, 0, stream>>>(counts, N, row_off, partials);
    k_scan_b<<<1, 64, 0, stream>>>(partials, nch);
    k_scan_c<<<nch, 1024, 0, stream>>>(row_off, partials, N, E);
    k_fill<<<(E + 255) / 256, 256, 0, stream>>>(head, tail, etype, E, row_off, cursor,
                                                c_head, c_tail, c_type);
    k_blk<<<(N + 255) / 256, 256, 0, stream>>>(row_off, N, blk_n0, blk_n1);

    const u16* cur = aggb0;
    u16* bufs[2] = {aggbA, aggbB};
    for (int hop = 0; hop < 3; hop++) {
        k_qproj<<<(N + 127) / 128, 256, 0, stream>>>(cur, (const uint4*)qwT_swz, qh, N);
        u16* nxt = bufs[hop & 1];
        int mode = (hop == 0) ? 0 : ((hop == 2) ? 2 : 1);
        k_fused<<<NB, 256, 0, stream>>>(cur, eembb, kwT, qh, c_head, c_tail, c_type,
                                        row_off, blk_n0, blk_n1, entity,
                                        nxt, (float*)d_out, mode);
        cur = nxt;
    }
}